// Round 8
// baseline (882.008 us; speedup 1.0000x reference)
//
#include <hip/hip_runtime.h>
#include <math.h>

// Problem constants (N=512 Clements mesh, L=512 layers, fixed by reference).
#define NPORT  512
#define NLAYER 512
#define NPAIR  256                      // even/odd layer pairs
#define CHUNK  4                        // layer-pairs per LDS stage
#define NCHUNK (NPAIR / CHUNK)          // 64 chunks
#define PPL    8                        // coefficient planes per pair
#define PLANES (CHUNK * PPL)            // 32 planes per chunk (32 KB)
#define ATTEN  0.9772372209558107f      // sqrt(10^(-0.2/10))

// Async global->LDS DMA, 16B per lane: LDS dst = uniform base + lane*16.
__device__ __forceinline__ void load_lds16(const float4* g, void* l) {
    __builtin_amdgcn_global_load_lds(
        (const __attribute__((address_space(1))) void*)g,
        (__attribute__((address_space(3))) void*)l, 16, 0, 0);
}

// Lane-shift shuffles via DPP (VALU pipe, no lgkm counter) — HW-validated in
// round 5 (absmax 1.8e-12). bound_ctrl=false: invalid lanes keep old value
// (safe: those operands are multiplied by identity-slot st=0 or overridden).
// wave_shr:1 (0x138): lane i <- lane i-1 (shfl_up);  lane 0 keeps old.
// wave_shl:1 (0x130): lane i <- lane i+1 (shfl_down); lane 63 keeps old.
__device__ __forceinline__ float dpp_up1(float x) {
    int r = __builtin_amdgcn_update_dpp(__float_as_int(x), __float_as_int(x),
                                        0x138, 0xF, 0xF, false);
    return __int_as_float(r);
}
__device__ __forceinline__ float dpp_down1(float x) {
    int r = __builtin_amdgcn_update_dpp(__float_as_int(x), __float_as_int(x),
                                        0x130, 0xF, 0xF, false);
    return __int_as_float(r);
}

// ---------------------------------------------------------------------------
// Coefficient table: per layer-pair p, 8 planes of 64 float4 (one per lane):
//   planes 0..3: even layer 2p,  lane t slot 4t+j (ports 8t+2j, 8t+2j+1)
//   planes 4..7: odd  layer 2p+1, lane t slot 4t+j (ports 8t+2j+1, 8t+2j+2)
// float4 = {cos(th)*A, sin(th)*A, cos(ph), sin(ph)}; invalid slot (odd,255)
// = identity {1,0,1,0}. The odd-layer LEFT-crossing coefficient for lane t
// (slot 4t-1) is lane t-1's plane-7 value (obtained via dpp_up1).
// ---------------------------------------------------------------------------
__global__ void coeff_kernel(const float* __restrict__ thetas,
                             const float* __restrict__ phis,
                             const int*   __restrict__ mzi_idx,
                             float4*      __restrict__ table) {
    int tid = blockIdx.x * blockDim.x + threadIdx.x;   // 0 .. NPAIR*8*64-1
    if (tid >= NPAIR * PPL * 64) return;
    int lane  = tid & 63;
    int plane = (tid >> 6) & 7;
    int p     = tid >> 9;

    int layer, slot, port_i;
    bool valid;
    if (plane < 4) {                    // even layer
        layer  = 2 * p;
        slot   = 4 * lane + plane;
        port_i = 2 * slot;
        valid  = true;
    } else {                            // odd layer local slots
        layer  = 2 * p + 1;
        slot   = 4 * lane + (plane - 4);
        port_i = 2 * slot + 1;
        valid  = (2 * slot + 2) < NPORT;   // slot 255 -> ports 511/512
    }

    float4 c = make_float4(1.f, 0.f, 1.f, 0.f);
    if (valid) {
        int m  = mzi_idx[layer * NPORT + port_i];
        float th = thetas[m], ph = phis[m];
        c.x = cosf(th) * ATTEN;
        c.y = sinf(th) * ATTEN;
        c.z = cosf(ph);
        c.w = sinf(ph);
    }
    table[(size_t)(p * PPL + plane) * 64 + lane] = c;
}

// ---------------------------------------------------------------------------
// Mesh propagation. 128 threads = 2 waves/block; each wave owns 2 rows
// (block b: wave w -> rows 4b+2w, 4b+2w+1). Lane t holds ports 8t..8t+7 of
// both rows in registers. 256 blocks -> 1 block/CU.
//
// SROA DISCIPLINE (rounds 6/7 lesson): the conditionally-initialized
// `PairCoef Bn; if(..) Bn = readPair(..); A = Bn;` rotation creates struct
// PHIs that the compiler demotes to scratch (VGPR pinned at 132, WRITE_SIZE
// 2048->8064 KB, 8x regression). Here the coefficient double-buffer is two
// NAMED structs with the 4-pair schedule written out explicitly — zero
// struct copies, zero conditional inits, every index literal.
// ---------------------------------------------------------------------------
struct PairCoef {
    float4 e[4];   // even-layer slots
    float4 o[4];   // odd-layer local slots
};

__global__ __launch_bounds__(128, 1)
void mesh_kernel(const float*  __restrict__ x,
                 const float4* __restrict__ table,
                 float*        __restrict__ out,
                 int B) {
    __shared__ float4 bufA[PLANES][64];   // 32 KB
    __shared__ float4 bufB[PLANES][64];   // 32 KB

    const int lane = threadIdx.x & 63;
    const int wid  = threadIdx.x >> 6;    // 0..1
    const int r0   = blockIdx.x * 4 + wid * 2;
    const int r1   = r0 + 1;
    const bool live0 = r0 < B;
    const bool live1 = r1 < B;

    // Load 8 consecutive real inputs per row -> complex state (im = 0).
    float sr0[8], si0[8], sr1[8], si1[8];
    {
        const float4* xp0 =
            (const float4*)(x + (size_t)(live0 ? r0 : 0) * NPORT) + lane * 2;
        const float4* xp1 =
            (const float4*)(x + (size_t)(live1 ? r1 : 0) * NPORT) + lane * 2;
        float4 a0 = xp0[0], b0 = xp0[1];
        float4 a1 = xp1[0], b1 = xp1[1];
        sr0[0]=a0.x; sr0[1]=a0.y; sr0[2]=a0.z; sr0[3]=a0.w;
        sr0[4]=b0.x; sr0[5]=b0.y; sr0[6]=b0.z; sr0[7]=b0.w;
        sr1[0]=a1.x; sr1[1]=a1.y; sr1[2]=a1.z; sr1[3]=a1.w;
        sr1[4]=b1.x; sr1[5]=b1.y; sr1[6]=b1.z; sr1[7]=b1.w;
#pragma unroll
        for (int j = 0; j < 8; ++j) { si0[j] = 0.f; si1[j] = 0.f; }
    }

    // DMA chunk c's 32 planes into buf; wave w takes planes 16w..16w+15.
    auto stage = [&](int c, float4 (*buf)[64]) {
        const float4* g = table + (size_t)c * (PLANES * 64) + lane;
#pragma unroll
        for (int k = 0; k < PLANES / 2; ++k) {
            int pl = wid * (PLANES / 2) + k;
            load_lds16(g + pl * 64, (void*)&buf[pl][0]);
        }
    };

    // One MZI on one row's arrays; p0/p1 literal at every call site.
    auto mzi = [](float (&sr)[8], float (&si)[8], const float4 c,
                  int p0, int p1) {
        float ct = c.x, st = c.y, er = c.z, ei = c.w;
        float ur = ct * sr[p0] + st * sr[p1];
        float ui = ct * si[p0] + st * si[p1];
        float lr = ct * sr[p1] - st * sr[p0];
        float li = ct * si[p1] - st * si[p0];
        sr[p0] = er * ur - ei * ui;
        si[p0] = er * ui + ei * ur;
        sr[p1] = lr;
        si[p1] = li;
    };

    auto readPair = [&](const float4 (*buf)[64], int pp, PairCoef& b) {
#pragma unroll
        for (int j = 0; j < 4; ++j) b.e[j] = buf[pp * PPL + j][lane];
#pragma unroll
        for (int j = 0; j < 4; ++j) b.o[j] = buf[pp * PPL + 4 + j][lane];
    };

    auto computePair = [&](const PairCoef& b) {
        // Even layer: ports (2j, 2j+1), all lane-local, rows interleaved.
#pragma unroll
        for (int j = 0; j < 4; ++j) {
            mzi(sr0, si0, b.e[j], 2 * j, 2 * j + 1);
            mzi(sr1, si1, b.e[j], 2 * j, 2 * j + 1);
        }

        // Odd layer. Coefficient shuffle once (row-independent).
        float lc = dpp_up1(b.o[3].x);       // left-crossing ct (slot 4t-1)
        float ls = dpp_up1(b.o[3].y);       // left-crossing st
        float ct4 = (lane > 0) ? lc : 1.f;  // lane 0: port 0 passthrough
        float st4 = (lane > 0) ? ls : 0.f;

        // Boundary moves for both rows (independent DPP ops, VALU pipe).
        float hr0 = dpp_down1(sr0[0]), hi0 = dpp_down1(si0[0]);
        float gr0 = dpp_up1(sr0[7]),   gi0 = dpp_up1(si0[7]);
        float hr1 = dpp_down1(sr1[0]), hi1 = dpp_down1(si1[0]);
        float gr1 = dpp_up1(sr1[7]),   gi1 = dpp_up1(si1[7]);

        // 3 internal MZIs: ports (2j+1, 2j+2), rows interleaved.
#pragma unroll
        for (int j = 0; j < 3; ++j) {
            mzi(sr0, si0, b.o[j], 2 * j + 1, 2 * j + 2);
            mzi(sr1, si1, b.o[j], 2 * j + 1, 2 * j + 2);
        }

        // Right crossing (upper = local port 7, lower = h): keep upper+phase.
        // Lane 63: slot 255 identity {1,0} -> sr7 passthrough, h unused (x0).
        {
            float ct = b.o[3].x, st = b.o[3].y, er = b.o[3].z, ei = b.o[3].w;
            float ur0 = ct * sr0[7] + st * hr0;
            float ui0 = ct * si0[7] + st * hi0;
            float ur1 = ct * sr1[7] + st * hr1;
            float ui1 = ct * si1[7] + st * hi1;
            sr0[7] = er * ur0 - ei * ui0;
            si0[7] = er * ui0 + ei * ur0;
            sr1[7] = er * ur1 - ei * ui1;
            si1[7] = er * ui1 + ei * ur1;
        }
        // Left crossing (upper = g, lower = local port 0): keep lower.
        {
            float a0 = ct4 * sr0[0] - st4 * gr0;
            float b0 = ct4 * si0[0] - st4 * gi0;
            float a1 = ct4 * sr1[0] - st4 * gr1;
            float b1 = ct4 * si1[0] - st4 * gi1;
            sr0[0] = a0; si0[0] = b0;
            sr1[0] = a1; si1[0] = b1;
        }
    };

    // Explicit software pipeline over the 4 pairs of a chunk: two NAMED
    // buffers, schedule fully unrolled by hand. No struct copies/PHIs.
    auto computeChunk = [&](const float4 (*buf)[64]) {
        PairCoef cb0, cb1;
        readPair(buf, 0, cb0);
        readPair(buf, 1, cb1);
        computePair(cb0);          // reads for pair 1 already in flight
        readPair(buf, 2, cb0);
        computePair(cb1);
        readPair(buf, 3, cb1);
        computePair(cb0);
        computePair(cb1);
    };

    stage(0, bufA);
    __syncthreads();

#pragma unroll 1
    for (int c = 0; c < NCHUNK; c += 2) {
        if (c + 1 < NCHUNK) stage(c + 1, bufB);
        computeChunk(bufA);
        __syncthreads();
        if (c + 2 < NCHUNK) stage(c + 2, bufA);
        computeChunk(bufB);
        __syncthreads();
    }

    // Photodetection: |E|^2, vectorized store, both rows.
    if (live0) {
        float4 o0 = make_float4(sr0[0]*sr0[0]+si0[0]*si0[0],
                                sr0[1]*sr0[1]+si0[1]*si0[1],
                                sr0[2]*sr0[2]+si0[2]*si0[2],
                                sr0[3]*sr0[3]+si0[3]*si0[3]);
        float4 o1 = make_float4(sr0[4]*sr0[4]+si0[4]*si0[4],
                                sr0[5]*sr0[5]+si0[5]*si0[5],
                                sr0[6]*sr0[6]+si0[6]*si0[6],
                                sr0[7]*sr0[7]+si0[7]*si0[7]);
        float4* op = (float4*)(out + (size_t)r0 * NPORT) + lane * 2;
        op[0] = o0;
        op[1] = o1;
    }
    if (live1) {
        float4 o0 = make_float4(sr1[0]*sr1[0]+si1[0]*si1[0],
                                sr1[1]*sr1[1]+si1[1]*si1[1],
                                sr1[2]*sr1[2]+si1[2]*si1[2],
                                sr1[3]*sr1[3]+si1[3]*si1[3]);
        float4 o1 = make_float4(sr1[4]*sr1[4]+si1[4]*si1[4],
                                sr1[5]*sr1[5]+si1[5]*si1[5],
                                sr1[6]*sr1[6]+si1[6]*si1[6],
                                sr1[7]*sr1[7]+si1[7]*si1[7]);
        float4* op = (float4*)(out + (size_t)r1 * NPORT) + lane * 2;
        op[0] = o0;
        op[1] = o1;
    }
}

// ---------------------------------------------------------------------------
// Fallback (ws too small for the table): trig inline, slow but correct.
// ---------------------------------------------------------------------------
__global__ __launch_bounds__(64)
void mesh_fallback(const float* __restrict__ x,
                   const float* __restrict__ thetas,
                   const float* __restrict__ phis,
                   const int*   __restrict__ mzi_idx,
                   float*       __restrict__ out) {
    const int lane = threadIdx.x;
    const int row  = blockIdx.x;

    const float4* xr = (const float4*)(x + (size_t)row * NPORT) + lane * 2;
    float4 xa = xr[0], xb = xr[1];
    float sr[8] = {xa.x, xa.y, xa.z, xa.w, xb.x, xb.y, xb.z, xb.w};
    float si[8] = {0.f, 0.f, 0.f, 0.f, 0.f, 0.f, 0.f, 0.f};

    auto mzi = [&](float ct, float st, float er, float ei, int p0, int p1) {
        float ur = ct * sr[p0] + st * sr[p1];
        float ui = ct * si[p0] + st * si[p1];
        float lr = ct * sr[p1] - st * sr[p0];
        float li = ct * si[p1] - st * si[p0];
        sr[p0] = er * ur - ei * ui;
        si[p0] = er * ui + ei * ur;
        sr[p1] = lr;
        si[p1] = li;
    };

    for (int l = 0; l < NLAYER; ++l) {
        if ((l & 1) == 0) {
#pragma unroll
            for (int j = 0; j < 4; ++j) {
                int m = mzi_idx[l * NPORT + (8 * lane + 2 * j)];
                float th = thetas[m], ph = phis[m];
                mzi(cosf(th) * ATTEN, sinf(th) * ATTEN, cosf(ph), sinf(ph),
                    2 * j, 2 * j + 1);
            }
        } else {
            float hr = __shfl_down(sr[0], 1);
            float hi = __shfl_down(si[0], 1);
#pragma unroll
            for (int j = 0; j < 3; ++j) {
                int m = mzi_idx[l * NPORT + (8 * lane + 2 * j + 1)];
                float th = thetas[m], ph = phis[m];
                mzi(cosf(th) * ATTEN, sinf(th) * ATTEN, cosf(ph), sinf(ph),
                    2 * j + 1, 2 * j + 2);
            }
            float ct = 1.f, st = 0.f, er = 1.f, ei = 0.f;
            if (lane < 63) {
                int m = mzi_idx[l * NPORT + (8 * lane + 7)];
                float th = thetas[m], ph = phis[m];
                ct = cosf(th) * ATTEN; st = sinf(th) * ATTEN;
                er = cosf(ph); ei = sinf(ph);
            }
            float ur = ct * sr[7] + st * hr;
            float ui = ct * si[7] + st * hi;
            float lr = ct * hr - st * sr[7];
            float li = ct * hi - st * si[7];
            sr[7] = er * ur - ei * ui;
            si[7] = er * ui + ei * ur;
            float rlr = __shfl_up(lr, 1);
            float rli = __shfl_up(li, 1);
            sr[0] = (lane > 0) ? rlr : sr[0];
            si[0] = (lane > 0) ? rli : si[0];
        }
    }

    float4 o0 = make_float4(sr[0] * sr[0] + si[0] * si[0],
                            sr[1] * sr[1] + si[1] * si[1],
                            sr[2] * sr[2] + si[2] * si[2],
                            sr[3] * sr[3] + si[3] * si[3]);
    float4 o1 = make_float4(sr[4] * sr[4] + si[4] * si[4],
                            sr[5] * sr[5] + si[5] * si[5],
                            sr[6] * sr[6] + si[6] * si[6],
                            sr[7] * sr[7] + si[7] * si[7]);
    float4* op = (float4*)(out + (size_t)row * NPORT) + lane * 2;
    op[0] = o0;
    op[1] = o1;
}

// ---------------------------------------------------------------------------
// Inputs (setup_inputs order): x[B*N] f32, thetas[M] f32, phis[M] f32,
// partner[L*N] i32 (unused), mzi_idx[L*N] i32, role[L*N] i32 (unused).
// ---------------------------------------------------------------------------
extern "C" void kernel_launch(void* const* d_in, const int* in_sizes, int n_in,
                              void* d_out, int out_size, void* d_ws,
                              size_t ws_size, hipStream_t stream) {
    const float* x       = (const float*)d_in[0];
    const float* thetas  = (const float*)d_in[1];
    const float* phis    = (const float*)d_in[2];
    const int*   mzi_idx = (const int*)d_in[4];
    float*       out     = (float*)d_out;

    int B = in_sizes[0] / NPORT;

    const size_t table_bytes = (size_t)NPAIR * PPL * 64 * sizeof(float4); // 2 MiB
    if (ws_size >= table_bytes) {
        float4* table = (float4*)d_ws;
        int nthreads = NPAIR * PPL * 64;
        coeff_kernel<<<(nthreads + 255) / 256, 256, 0, stream>>>(
            thetas, phis, mzi_idx, table);
        int nblk = (B + 3) / 4;      // 4 rows per block (2 waves x 2 rows)
        mesh_kernel<<<nblk, 128, 0, stream>>>(x, table, out, B);
    } else {
        mesh_fallback<<<B, 64, 0, stream>>>(x, thetas, phis, mzi_idx, out);
    }
}

// Round 9
// 241.147 us; speedup vs baseline: 3.6575x; 3.6575x over previous
//
#include <hip/hip_runtime.h>
#include <math.h>

// Problem constants (N=512 Clements mesh, L=512 layers, fixed by reference).
#define NPORT  512
#define NLAYER 512
#define NPAIR  256                      // even/odd layer pairs
#define CHUNK  4                        // layer-pairs per LDS stage
#define NCHUNK (NPAIR / CHUNK)          // 64 chunks
#define PPL    8                        // coefficient planes per pair
#define PLANES (CHUNK * PPL)            // 32 planes per chunk (32 KB)
#define ATTEN  0.9772372209558107f      // sqrt(10^(-0.2/10))

// Async global->LDS DMA, 16B per lane: LDS dst = uniform base + lane*16.
__device__ __forceinline__ void load_lds16(const float4* g, void* l) {
    __builtin_amdgcn_global_load_lds(
        (const __attribute__((address_space(1))) void*)g,
        (__attribute__((address_space(3))) void*)l, 16, 0, 0);
}

// Lane-shift shuffles via DPP (VALU pipe, no lgkm counter) — HW-validated in
// round 5 (absmax 1.8e-12). bound_ctrl=false: invalid lanes keep old value
// (safe: those operands are multiplied by identity-slot st=0 or overridden).
// wave_shr:1 (0x138): lane i <- lane i-1 (shfl_up);  lane 0 keeps old.
// wave_shl:1 (0x130): lane i <- lane i+1 (shfl_down); lane 63 keeps old.
__device__ __forceinline__ float dpp_up1(float x) {
    int r = __builtin_amdgcn_update_dpp(__float_as_int(x), __float_as_int(x),
                                        0x138, 0xF, 0xF, false);
    return __int_as_float(r);
}
__device__ __forceinline__ float dpp_down1(float x) {
    int r = __builtin_amdgcn_update_dpp(__float_as_int(x), __float_as_int(x),
                                        0x130, 0xF, 0xF, false);
    return __int_as_float(r);
}

// ---------------------------------------------------------------------------
// Coefficient table: per layer-pair p, 8 planes of 64 float4 (one per lane):
//   planes 0..3: even layer 2p,  lane t slot 4t+j (ports 8t+2j, 8t+2j+1)
//   planes 4..7: odd  layer 2p+1, lane t slot 4t+j (ports 8t+2j+1, 8t+2j+2)
// float4 = {cos(th)*A, sin(th)*A, cos(ph), sin(ph)}; invalid slot (odd,255)
// = identity {1,0,1,0}. The odd-layer LEFT-crossing coefficient for lane t
// (slot 4t-1) is lane t-1's plane-7 value (obtained via dpp_up1).
// ---------------------------------------------------------------------------
__global__ void coeff_kernel(const float* __restrict__ thetas,
                             const float* __restrict__ phis,
                             const int*   __restrict__ mzi_idx,
                             float4*      __restrict__ table) {
    int tid = blockIdx.x * blockDim.x + threadIdx.x;   // 0 .. NPAIR*8*64-1
    if (tid >= NPAIR * PPL * 64) return;
    int lane  = tid & 63;
    int plane = (tid >> 6) & 7;
    int p     = tid >> 9;

    int layer, slot, port_i;
    bool valid;
    if (plane < 4) {                    // even layer
        layer  = 2 * p;
        slot   = 4 * lane + plane;
        port_i = 2 * slot;
        valid  = true;
    } else {                            // odd layer local slots
        layer  = 2 * p + 1;
        slot   = 4 * lane + (plane - 4);
        port_i = 2 * slot + 1;
        valid  = (2 * slot + 2) < NPORT;   // slot 255 -> ports 511/512
    }

    float4 c = make_float4(1.f, 0.f, 1.f, 0.f);
    if (valid) {
        int m  = mzi_idx[layer * NPORT + port_i];
        float th = thetas[m], ph = phis[m];
        c.x = cosf(th) * ATTEN;
        c.y = sinf(th) * ATTEN;
        c.z = cosf(ph);
        c.w = sinf(ph);
    }
    table[(size_t)(p * PPL + plane) * 64 + lane] = c;
}

// ---------------------------------------------------------------------------
// One MZI on named scalar lvalues; C is a float4 {ct,st,cph,sph}.
// Upper port (p) gets the phase; lower (q) does not.
// ---------------------------------------------------------------------------
#define MZI(C, pr, pi, qr, qi) do {                                  \
    float _ur = (C).x * (pr) + (C).y * (qr);                         \
    float _ui = (C).x * (pi) + (C).y * (qi);                         \
    float _lr = (C).x * (qr) - (C).y * (pr);                         \
    float _li = (C).x * (qi) - (C).y * (pi);                         \
    (pr) = (C).z * _ur - (C).w * _ui;                                \
    (pi) = (C).z * _ui + (C).w * _ur;                                \
    (qr) = _lr; (qi) = _li; } while (0)

// Even layer: 4 lane-local MZIs on ports (2j, 2j+1), applied to both rows.
#define EVEN_L do {                                                  \
    MZI(e0, x0r, x0i, x1r, x1i);  MZI(e0, y0r, y0i, y1r, y1i);       \
    MZI(e1, x2r, x2i, x3r, x3i);  MZI(e1, y2r, y2i, y3r, y3i);       \
    MZI(e2, x4r, x4i, x5r, x5i);  MZI(e2, y4r, y4i, y5r, y5i);       \
    MZI(e3, x6r, x6i, x7r, x7i);  MZI(e3, y6r, y6i, y7r, y7i); } while (0)

// Odd layer: boundary values captured via DPP on OLD x0/x7 (untouched by the
// internal MZIs), 3 internal MZIs, then right/left crossings. Lane 63 right
// crossing has identity coeffs (port 511 passthrough); lane 0 left crossing
// forced to identity (port 0 passthrough).
#define ODD_L do {                                                   \
    float _lc = dpp_up1(o3.x), _ls = dpp_up1(o3.y);                  \
    float _ct4 = (lane > 0) ? _lc : 1.f;                             \
    float _st4 = (lane > 0) ? _ls : 0.f;                             \
    float _hxr = dpp_down1(x0r), _hxi = dpp_down1(x0i);              \
    float _gxr = dpp_up1(x7r),   _gxi = dpp_up1(x7i);                \
    float _hyr = dpp_down1(y0r), _hyi = dpp_down1(y0i);              \
    float _gyr = dpp_up1(y7r),   _gyi = dpp_up1(y7i);                \
    MZI(o0, x1r, x1i, x2r, x2i);  MZI(o0, y1r, y1i, y2r, y2i);       \
    MZI(o1, x3r, x3i, x4r, x4i);  MZI(o1, y3r, y3i, y4r, y4i);       \
    MZI(o2, x5r, x5i, x6r, x6i);  MZI(o2, y5r, y5i, y6r, y6i);       \
    { float _ur = o3.x * x7r + o3.y * _hxr;                          \
      float _ui = o3.x * x7i + o3.y * _hxi;                          \
      x7r = o3.z * _ur - o3.w * _ui;                                 \
      x7i = o3.z * _ui + o3.w * _ur; }                               \
    { float _ur = o3.x * y7r + o3.y * _hyr;                          \
      float _ui = o3.x * y7i + o3.y * _hyi;                          \
      y7r = o3.z * _ur - o3.w * _ui;                                 \
      y7i = o3.z * _ui + o3.w * _ur; }                               \
    { float _a = _ct4 * x0r - _st4 * _gxr;                           \
      float _b = _ct4 * x0i - _st4 * _gxi;                           \
      x0r = _a; x0i = _b; }                                          \
    { float _a = _ct4 * y0r - _st4 * _gyr;                           \
      float _b = _ct4 * y0i - _st4 * _gyi;                           \
      y0r = _a; y0i = _b; } } while (0)

// Coefficient reads: 4 x ds_read_b128 into named float4s.
#define RDE(buf, p) do {                                             \
    e0 = (buf)[(p) * PPL + 0][lane]; e1 = (buf)[(p) * PPL + 1][lane];\
    e2 = (buf)[(p) * PPL + 2][lane]; e3 = (buf)[(p) * PPL + 3][lane];\
    } while (0)
#define RDO(buf, p) do {                                             \
    o0 = (buf)[(p) * PPL + 4][lane]; o1 = (buf)[(p) * PPL + 5][lane];\
    o2 = (buf)[(p) * PPL + 6][lane]; o3 = (buf)[(p) * PPL + 7][lane];\
    } while (0)

// One chunk (4 layer-pairs), half-layer software pipeline: each 4-read burst
// is issued one half-layer (~190 issue-cyc) before its use.
#define CHUNK_BODY(buf) do {                                         \
    RDE(buf, 0); RDO(buf, 0);                                        \
    EVEN_L; RDE(buf, 1); ODD_L; RDO(buf, 1);                         \
    EVEN_L; RDE(buf, 2); ODD_L; RDO(buf, 2);                         \
    EVEN_L; RDE(buf, 3); ODD_L; RDO(buf, 3);                         \
    EVEN_L; ODD_L; } while (0)

// ---------------------------------------------------------------------------
// Mesh propagation. ONE WAVE PER BLOCK (64 thr); each wave owns 2 rows.
// 512 blocks -> 2 independent blocks/CU (LDS 64KB each, 128/160 KB): private
// DMA double-buffers, no inter-wave barrier coupling (__syncthreads in a
// 1-wave block is just the wave's own waitcnt), and the two waves/CU hide
// each other's drains (m114 co-scheduling).
//
// ALLOCA-FREE (rounds 6-8 lesson): every failing 2-row variant kept state or
// coefficients in local arrays/structs; the backend demoted the allocas to
// scratch (VGPR pinned 132, WRITE_SIZE 2048->~8000 KB, 8x regression). Here
// ALL per-thread data is individually-named scalars/float4s manipulated by
// macros — there is no alloca to demote.
// ---------------------------------------------------------------------------
__global__ __launch_bounds__(64, 1)
void mesh_kernel(const float*  __restrict__ x,
                 const float4* __restrict__ table,
                 float*        __restrict__ out,
                 int B) {
    __shared__ float4 bufA[PLANES][64];   // 32 KB
    __shared__ float4 bufB[PLANES][64];   // 32 KB

    const int lane = threadIdx.x;         // 0..63
    const int r0   = blockIdx.x * 2;
    const int r1   = r0 + 1;
    const bool live0 = r0 < B;
    const bool live1 = r1 < B;

    // Row 0 state: ports 8t..8t+7, complex (im = 0 initially).
    float x0r, x1r, x2r, x3r, x4r, x5r, x6r, x7r;
    float x0i, x1i, x2i, x3i, x4i, x5i, x6i, x7i;
    float y0r, y1r, y2r, y3r, y4r, y5r, y6r, y7r;
    float y0i, y1i, y2i, y3i, y4i, y5i, y6i, y7i;
    {
        const float4* xp0 =
            (const float4*)(x + (size_t)(live0 ? r0 : 0) * NPORT) + lane * 2;
        const float4* xp1 =
            (const float4*)(x + (size_t)(live1 ? r1 : 0) * NPORT) + lane * 2;
        float4 a0 = xp0[0], b0 = xp0[1];
        float4 a1 = xp1[0], b1 = xp1[1];
        x0r = a0.x; x1r = a0.y; x2r = a0.z; x3r = a0.w;
        x4r = b0.x; x5r = b0.y; x6r = b0.z; x7r = b0.w;
        y0r = a1.x; y1r = a1.y; y2r = a1.z; y3r = a1.w;
        y4r = b1.x; y5r = b1.y; y6r = b1.z; y7r = b1.w;
        x0i = x1i = x2i = x3i = x4i = x5i = x6i = x7i = 0.f;
        y0i = y1i = y2i = y3i = y4i = y5i = y6i = y7i = 0.f;
    }

    // Coefficient registers (renamed per pipeline stage; no aggregates).
    float4 e0, e1, e2, e3, o0, o1, o2, o3;

    // DMA chunk c's 32 planes into buf (single wave stages everything).
    auto stage = [&](int c, float4 (*buf)[64]) {
        const float4* g = table + (size_t)c * (PLANES * 64) + lane;
#pragma unroll
        for (int k = 0; k < PLANES; ++k)
            load_lds16(g + k * 64, (void*)&buf[k][0]);
    };

    stage(0, bufA);
    __syncthreads();

#pragma unroll 1
    for (int c = 0; c < NCHUNK; c += 2) {
        if (c + 1 < NCHUNK) stage(c + 1, bufB);
        CHUNK_BODY(bufA);
        __syncthreads();
        if (c + 2 < NCHUNK) stage(c + 2, bufA);
        CHUNK_BODY(bufB);
        __syncthreads();
    }

    // Photodetection: |E|^2, vectorized store, both rows.
    if (live0) {
        float4 u = make_float4(x0r * x0r + x0i * x0i, x1r * x1r + x1i * x1i,
                               x2r * x2r + x2i * x2i, x3r * x3r + x3i * x3i);
        float4 v = make_float4(x4r * x4r + x4i * x4i, x5r * x5r + x5i * x5i,
                               x6r * x6r + x6i * x6i, x7r * x7r + x7i * x7i);
        float4* op = (float4*)(out + (size_t)r0 * NPORT) + lane * 2;
        op[0] = u;
        op[1] = v;
    }
    if (live1) {
        float4 u = make_float4(y0r * y0r + y0i * y0i, y1r * y1r + y1i * y1i,
                               y2r * y2r + y2i * y2i, y3r * y3r + y3i * y3i);
        float4 v = make_float4(y4r * y4r + y4i * y4i, y5r * y5r + y5i * y5i,
                               y6r * y6r + y6i * y6i, y7r * y7r + y7i * y7i);
        float4* op = (float4*)(out + (size_t)r1 * NPORT) + lane * 2;
        op[0] = u;
        op[1] = v;
    }
}

// ---------------------------------------------------------------------------
// Fallback (ws too small for the table): trig inline, slow but correct.
// ---------------------------------------------------------------------------
__global__ __launch_bounds__(64)
void mesh_fallback(const float* __restrict__ x,
                   const float* __restrict__ thetas,
                   const float* __restrict__ phis,
                   const int*   __restrict__ mzi_idx,
                   float*       __restrict__ out) {
    const int lane = threadIdx.x;
    const int row  = blockIdx.x;

    const float4* xr = (const float4*)(x + (size_t)row * NPORT) + lane * 2;
    float4 xa = xr[0], xb = xr[1];
    float sr[8] = {xa.x, xa.y, xa.z, xa.w, xb.x, xb.y, xb.z, xb.w};
    float si[8] = {0.f, 0.f, 0.f, 0.f, 0.f, 0.f, 0.f, 0.f};

    auto mzi = [&](float ct, float st, float er, float ei, int p0, int p1) {
        float ur = ct * sr[p0] + st * sr[p1];
        float ui = ct * si[p0] + st * si[p1];
        float lr = ct * sr[p1] - st * sr[p0];
        float li = ct * si[p1] - st * si[p0];
        sr[p0] = er * ur - ei * ui;
        si[p0] = er * ui + ei * ur;
        sr[p1] = lr;
        si[p1] = li;
    };

    for (int l = 0; l < NLAYER; ++l) {
        if ((l & 1) == 0) {
#pragma unroll
            for (int j = 0; j < 4; ++j) {
                int m = mzi_idx[l * NPORT + (8 * lane + 2 * j)];
                float th = thetas[m], ph = phis[m];
                mzi(cosf(th) * ATTEN, sinf(th) * ATTEN, cosf(ph), sinf(ph),
                    2 * j, 2 * j + 1);
            }
        } else {
            float hr = __shfl_down(sr[0], 1);
            float hi = __shfl_down(si[0], 1);
#pragma unroll
            for (int j = 0; j < 3; ++j) {
                int m = mzi_idx[l * NPORT + (8 * lane + 2 * j + 1)];
                float th = thetas[m], ph = phis[m];
                mzi(cosf(th) * ATTEN, sinf(th) * ATTEN, cosf(ph), sinf(ph),
                    2 * j + 1, 2 * j + 2);
            }
            float ct = 1.f, st = 0.f, er = 1.f, ei = 0.f;
            if (lane < 63) {
                int m = mzi_idx[l * NPORT + (8 * lane + 7)];
                float th = thetas[m], ph = phis[m];
                ct = cosf(th) * ATTEN; st = sinf(th) * ATTEN;
                er = cosf(ph); ei = sinf(ph);
            }
            float ur = ct * sr[7] + st * hr;
            float ui = ct * si[7] + st * hi;
            float lr = ct * hr - st * sr[7];
            float li = ct * hi - st * si[7];
            sr[7] = er * ur - ei * ui;
            si[7] = er * ui + ei * ur;
            float rlr = __shfl_up(lr, 1);
            float rli = __shfl_up(li, 1);
            sr[0] = (lane > 0) ? rlr : sr[0];
            si[0] = (lane > 0) ? rli : si[0];
        }
    }

    float4 o0 = make_float4(sr[0] * sr[0] + si[0] * si[0],
                            sr[1] * sr[1] + si[1] * si[1],
                            sr[2] * sr[2] + si[2] * si[2],
                            sr[3] * sr[3] + si[3] * si[3]);
    float4 o1 = make_float4(sr[4] * sr[4] + si[4] * si[4],
                            sr[5] * sr[5] + si[5] * si[5],
                            sr[6] * sr[6] + si[6] * si[6],
                            sr[7] * sr[7] + si[7] * si[7]);
    float4* op = (float4*)(out + (size_t)row * NPORT) + lane * 2;
    op[0] = o0;
    op[1] = o1;
}

// ---------------------------------------------------------------------------
// Inputs (setup_inputs order): x[B*N] f32, thetas[M] f32, phis[M] f32,
// partner[L*N] i32 (unused), mzi_idx[L*N] i32, role[L*N] i32 (unused).
// ---------------------------------------------------------------------------
extern "C" void kernel_launch(void* const* d_in, const int* in_sizes, int n_in,
                              void* d_out, int out_size, void* d_ws,
                              size_t ws_size, hipStream_t stream) {
    const float* x       = (const float*)d_in[0];
    const float* thetas  = (const float*)d_in[1];
    const float* phis    = (const float*)d_in[2];
    const int*   mzi_idx = (const int*)d_in[4];
    float*       out     = (float*)d_out;

    int B = in_sizes[0] / NPORT;

    const size_t table_bytes = (size_t)NPAIR * PPL * 64 * sizeof(float4); // 2 MiB
    if (ws_size >= table_bytes) {
        float4* table = (float4*)d_ws;
        int nthreads = NPAIR * PPL * 64;
        coeff_kernel<<<(nthreads + 255) / 256, 256, 0, stream>>>(
            thetas, phis, mzi_idx, table);
        int nblk = (B + 1) / 2;      // 2 rows per block (1 wave x 2 rows)
        mesh_kernel<<<nblk, 64, 0, stream>>>(x, table, out, B);
    } else {
        mesh_fallback<<<B, 64, 0, stream>>>(x, thetas, phis, mzi_idx, out);
    }
}

// Round 10
// 214.767 us; speedup vs baseline: 4.1068x; 1.1228x over previous
//
#include <hip/hip_runtime.h>
#include <math.h>

// Problem constants (N=512 Clements mesh, L=512 layers, fixed by reference).
#define NPORT  512
#define NLAYER 512
#define NPAIR  256                      // even/odd layer pairs
#define PPL    8                        // coefficient planes per pair
#define ATTEN  0.9772372209558107f      // sqrt(10^(-0.2/10))

// Lane-shift shuffles via DPP (VALU pipe, no lgkm counter) — HW-validated
// rounds 5/9 (absmax 1.8e-12). bound_ctrl=false: edge lanes keep old value
// (safe: those operands are multiplied by identity-slot st=0 or overridden).
__device__ __forceinline__ float dpp_up1(float x) {
    int r = __builtin_amdgcn_update_dpp(__float_as_int(x), __float_as_int(x),
                                        0x138, 0xF, 0xF, false);
    return __int_as_float(r);
}
__device__ __forceinline__ float dpp_down1(float x) {
    int r = __builtin_amdgcn_update_dpp(__float_as_int(x), __float_as_int(x),
                                        0x130, 0xF, 0xF, false);
    return __int_as_float(r);
}

// ---------------------------------------------------------------------------
// Coefficient table: per layer-pair p, 8 planes of 64 float4 (one per lane):
//   planes 0..3: even layer 2p,  lane t slot 4t+j (ports 8t+2j, 8t+2j+1)
//   planes 4..7: odd  layer 2p+1, lane t slot 4t+j (ports 8t+2j+1, 8t+2j+2)
// float4 = {cos(th)*A, sin(th)*A, cos(ph), sin(ph)}; invalid slot (odd,255)
// = identity {1,0,1,0}. Odd-layer LEFT-crossing coef for lane t = lane t-1's
// plane-7 value (dpp_up1). Plane-major: lane t reads (p*8+j)*64 + t -> each
// global_load_dwordx4 is a fully-coalesced 1 KB wave transaction.
// ---------------------------------------------------------------------------
__global__ void coeff_kernel(const float* __restrict__ thetas,
                             const float* __restrict__ phis,
                             const int*   __restrict__ mzi_idx,
                             float4*      __restrict__ table) {
    int tid = blockIdx.x * blockDim.x + threadIdx.x;   // 0 .. NPAIR*8*64-1
    if (tid >= NPAIR * PPL * 64) return;
    int lane  = tid & 63;
    int plane = (tid >> 6) & 7;
    int p     = tid >> 9;

    int layer, slot, port_i;
    bool valid;
    if (plane < 4) {                    // even layer
        layer  = 2 * p;
        slot   = 4 * lane + plane;
        port_i = 2 * slot;
        valid  = true;
    } else {                            // odd layer local slots
        layer  = 2 * p + 1;
        slot   = 4 * lane + (plane - 4);
        port_i = 2 * slot + 1;
        valid  = (2 * slot + 2) < NPORT;   // slot 255 -> ports 511/512
    }

    float4 c = make_float4(1.f, 0.f, 1.f, 0.f);
    if (valid) {
        int m  = mzi_idx[layer * NPORT + port_i];
        float th = thetas[m], ph = phis[m];
        c.x = cosf(th) * ATTEN;
        c.y = sinf(th) * ATTEN;
        c.z = cosf(ph);
        c.w = sinf(ph);
    }
    table[(size_t)(p * PPL + plane) * 64 + lane] = c;
}

// ---------------------------------------------------------------------------
// One MZI on named scalar lvalues; C is a float4 {ct,st,cph,sph}.
// Upper port (p) gets the phase; lower (q) does not.
// ---------------------------------------------------------------------------
#define MZI(C, pr, pi, qr, qi) do {                                  \
    float _ur = (C).x * (pr) + (C).y * (qr);                         \
    float _ui = (C).x * (pi) + (C).y * (qi);                         \
    float _lr = (C).x * (qr) - (C).y * (pr);                         \
    float _li = (C).x * (qi) - (C).y * (pi);                         \
    (pr) = (C).z * _ur - (C).w * _ui;                                \
    (pi) = (C).z * _ui + (C).w * _ur;                                \
    (qr) = _lr; (qi) = _li; } while (0)

// Full layer-pair (even + odd) on one row held in 16 named scalars.
// Odd layer: boundary values captured via DPP on OLD x0/x7 (untouched by the
// internal MZIs). Lane 63 right crossing = identity coeffs (port 511
// passthrough); lane 0 left crossing forced to identity (port 0 passthrough).
// Numerics HW-validated in rounds 5/9.
#define PAIR_BODY(E0, E1, E2, E3, O0, O1, O2, O3) do {               \
    MZI(E0, x0r, x0i, x1r, x1i);                                     \
    MZI(E1, x2r, x2i, x3r, x3i);                                     \
    MZI(E2, x4r, x4i, x5r, x5i);                                     \
    MZI(E3, x6r, x6i, x7r, x7i);                                     \
    float _lc = dpp_up1((O3).x), _ls = dpp_up1((O3).y);              \
    float _ct4 = (lane > 0) ? _lc : 1.f;                             \
    float _st4 = (lane > 0) ? _ls : 0.f;                             \
    float _hxr = dpp_down1(x0r), _hxi = dpp_down1(x0i);              \
    float _gxr = dpp_up1(x7r),   _gxi = dpp_up1(x7i);                \
    MZI(O0, x1r, x1i, x2r, x2i);                                     \
    MZI(O1, x3r, x3i, x4r, x4i);                                     \
    MZI(O2, x5r, x5i, x6r, x6i);                                     \
    { float _ur = (O3).x * x7r + (O3).y * _hxr;                      \
      float _ui = (O3).x * x7i + (O3).y * _hxi;                      \
      x7r = (O3).z * _ur - (O3).w * _ui;                             \
      x7i = (O3).z * _ui + (O3).w * _ur; }                           \
    { float _a = _ct4 * x0r - _st4 * _gxr;                           \
      float _b = _ct4 * x0i - _st4 * _gxi;                           \
      x0r = _a; x0i = _b; } } while (0)

// Load one pair's 8 planes into 8 named float4 regs (8 coalesced dwordx4),
// then advance the running pointer. The WAR dependency on these named regs
// pins the prefetch window structurally: the loads cannot sink below their
// first use, nor hoist above the previous pair's last use of the same regs.
#define RD(E0, E1, E2, E3, O0, O1, O2, O3) do {                      \
    E0 = gp[0 * 64]; E1 = gp[1 * 64]; E2 = gp[2 * 64];               \
    E3 = gp[3 * 64]; O0 = gp[4 * 64]; O1 = gp[5 * 64];               \
    O2 = gp[6 * 64]; O3 = gp[7 * 64]; gp += PPL * 64; } while (0)

#define RD_A RD(ea0, ea1, ea2, ea3, oa0, oa1, oa2, oa3)
#define RD_B RD(eb0, eb1, eb2, eb3, ob0, ob1, ob2, ob3)
#define PAIR_A PAIR_BODY(ea0, ea1, ea2, ea3, oa0, oa1, oa2, oa3)
#define PAIR_B PAIR_BODY(eb0, eb1, eb2, eb3, ob0, ob1, ob2, ob3)

// ---------------------------------------------------------------------------
// Mesh propagation, NO LDS. 256 threads = 4 waves/block, one row per wave
// (row = blockIdx*4 + waveid); 256 blocks -> 1 block/CU, 4 waves on 4 SIMDs
// (round-9 lesson: keep 4 waves/CU — TLP is the only stall-hiding at this
// grid size). Coefficients stream global->VGPR through L1/L2 (table = 2 MB,
// fits per-XCD L2; 4 co-located waves share the L1 stream). Double-buffered
// named register sets give each pair's loads a full pair (~280 issue-cyc) of
// cover > ~200 cyc L2 latency; compiler emits fine-grained vmcnt waits.
// No barriers, no DMA, no lgkm ops at all. Alloca-free (rounds 6-9 lesson).
// ---------------------------------------------------------------------------
__global__ __launch_bounds__(256, 1)
void mesh_kernel(const float*  __restrict__ x,
                 const float4* __restrict__ table,
                 float*        __restrict__ out,
                 int B) {
    const int lane = threadIdx.x & 63;
    const int wid  = threadIdx.x >> 6;    // 0..3
    const int row  = blockIdx.x * 4 + wid;
    const bool live = row < B;

    // Load 8 consecutive real inputs -> complex state (im = 0), named regs.
    float x0r, x1r, x2r, x3r, x4r, x5r, x6r, x7r;
    float x0i, x1i, x2i, x3i, x4i, x5i, x6i, x7i;
    {
        const float4* xp =
            (const float4*)(x + (size_t)(live ? row : 0) * NPORT) + lane * 2;
        float4 a = xp[0], b = xp[1];
        x0r = a.x; x1r = a.y; x2r = a.z; x3r = a.w;
        x4r = b.x; x5r = b.y; x6r = b.z; x7r = b.w;
        x0i = x1i = x2i = x3i = x4i = x5i = x6i = x7i = 0.f;
    }

    // Coefficient double-buffer: 16 named float4 (64 VGPRs).
    float4 ea0, ea1, ea2, ea3, oa0, oa1, oa2, oa3;
    float4 eb0, eb1, eb2, eb3, ob0, ob1, ob2, ob3;

    const float4* gp = table + lane;      // running pointer, +512 per pair

    RD_A;                                  // pair 0
#pragma unroll 1
    for (int p = 0; p < NPAIR - 2; p += 2) {
        RD_B;                              // load pair p+1
        PAIR_A;                            // compute pair p   (covers B)
        RD_A;                              // load pair p+2
        PAIR_B;                            // compute pair p+1 (covers A)
    }
    RD_B;                                  // pair 255
    PAIR_A;                                // compute pair 254
    PAIR_B;                                // compute pair 255

    // Photodetection: |E|^2, vectorized store.
    if (live) {
        float4 u = make_float4(x0r * x0r + x0i * x0i, x1r * x1r + x1i * x1i,
                               x2r * x2r + x2i * x2i, x3r * x3r + x3i * x3i);
        float4 v = make_float4(x4r * x4r + x4i * x4i, x5r * x5r + x5i * x5i,
                               x6r * x6r + x6i * x6i, x7r * x7r + x7i * x7i);
        float4* op = (float4*)(out + (size_t)row * NPORT) + lane * 2;
        op[0] = u;
        op[1] = v;
    }
}

// ---------------------------------------------------------------------------
// Fallback (ws too small for the table): trig inline, slow but correct.
// ---------------------------------------------------------------------------
__global__ __launch_bounds__(64)
void mesh_fallback(const float* __restrict__ x,
                   const float* __restrict__ thetas,
                   const float* __restrict__ phis,
                   const int*   __restrict__ mzi_idx,
                   float*       __restrict__ out) {
    const int lane = threadIdx.x;
    const int row  = blockIdx.x;

    const float4* xr = (const float4*)(x + (size_t)row * NPORT) + lane * 2;
    float4 xa = xr[0], xb = xr[1];
    float sr[8] = {xa.x, xa.y, xa.z, xa.w, xb.x, xb.y, xb.z, xb.w};
    float si[8] = {0.f, 0.f, 0.f, 0.f, 0.f, 0.f, 0.f, 0.f};

    auto mzi = [&](float ct, float st, float er, float ei, int p0, int p1) {
        float ur = ct * sr[p0] + st * sr[p1];
        float ui = ct * si[p0] + st * si[p1];
        float lr = ct * sr[p1] - st * sr[p0];
        float li = ct * si[p1] - st * si[p0];
        sr[p0] = er * ur - ei * ui;
        si[p0] = er * ui + ei * ur;
        sr[p1] = lr;
        si[p1] = li;
    };

    for (int l = 0; l < NLAYER; ++l) {
        if ((l & 1) == 0) {
#pragma unroll
            for (int j = 0; j < 4; ++j) {
                int m = mzi_idx[l * NPORT + (8 * lane + 2 * j)];
                float th = thetas[m], ph = phis[m];
                mzi(cosf(th) * ATTEN, sinf(th) * ATTEN, cosf(ph), sinf(ph),
                    2 * j, 2 * j + 1);
            }
        } else {
            float hr = __shfl_down(sr[0], 1);
            float hi = __shfl_down(si[0], 1);
#pragma unroll
            for (int j = 0; j < 3; ++j) {
                int m = mzi_idx[l * NPORT + (8 * lane + 2 * j + 1)];
                float th = thetas[m], ph = phis[m];
                mzi(cosf(th) * ATTEN, sinf(th) * ATTEN, cosf(ph), sinf(ph),
                    2 * j + 1, 2 * j + 2);
            }
            float ct = 1.f, st = 0.f, er = 1.f, ei = 0.f;
            if (lane < 63) {
                int m = mzi_idx[l * NPORT + (8 * lane + 7)];
                float th = thetas[m], ph = phis[m];
                ct = cosf(th) * ATTEN; st = sinf(th) * ATTEN;
                er = cosf(ph); ei = sinf(ph);
            }
            float ur = ct * sr[7] + st * hr;
            float ui = ct * si[7] + st * hi;
            float lr = ct * hr - st * sr[7];
            float li = ct * hi - st * si[7];
            sr[7] = er * ur - ei * ui;
            si[7] = er * ui + ei * ur;
            float rlr = __shfl_up(lr, 1);
            float rli = __shfl_up(li, 1);
            sr[0] = (lane > 0) ? rlr : sr[0];
            si[0] = (lane > 0) ? rli : si[0];
        }
    }

    float4 o0 = make_float4(sr[0] * sr[0] + si[0] * si[0],
                            sr[1] * sr[1] + si[1] * si[1],
                            sr[2] * sr[2] + si[2] * si[2],
                            sr[3] * sr[3] + si[3] * si[3]);
    float4 o1 = make_float4(sr[4] * sr[4] + si[4] * si[4],
                            sr[5] * sr[5] + si[5] * si[5],
                            sr[6] * sr[6] + si[6] * si[6],
                            sr[7] * sr[7] + si[7] * si[7]);
    float4* op = (float4*)(out + (size_t)row * NPORT) + lane * 2;
    op[0] = o0;
    op[1] = o1;
}

// ---------------------------------------------------------------------------
// Inputs (setup_inputs order): x[B*N] f32, thetas[M] f32, phis[M] f32,
// partner[L*N] i32 (unused), mzi_idx[L*N] i32, role[L*N] i32 (unused).
// ---------------------------------------------------------------------------
extern "C" void kernel_launch(void* const* d_in, const int* in_sizes, int n_in,
                              void* d_out, int out_size, void* d_ws,
                              size_t ws_size, hipStream_t stream) {
    const float* x       = (const float*)d_in[0];
    const float* thetas  = (const float*)d_in[1];
    const float* phis    = (const float*)d_in[2];
    const int*   mzi_idx = (const int*)d_in[4];
    float*       out     = (float*)d_out;

    int B = in_sizes[0] / NPORT;

    const size_t table_bytes = (size_t)NPAIR * PPL * 64 * sizeof(float4); // 2 MiB
    if (ws_size >= table_bytes) {
        float4* table = (float4*)d_ws;
        int nthreads = NPAIR * PPL * 64;
        coeff_kernel<<<(nthreads + 255) / 256, 256, 0, stream>>>(
            thetas, phis, mzi_idx, table);
        int nblk = (B + 3) / 4;      // 4 rows per block (4 waves x 1 row)
        mesh_kernel<<<nblk, 256, 0, stream>>>(x, table, out, B);
    } else {
        mesh_fallback<<<B, 64, 0, stream>>>(x, thetas, phis, mzi_idx, out);
    }
}